// Round 12
// baseline (53.066 us; speedup 1.0000x reference)
//
#include <hip/hip_runtime.h>

// CARAFE naive upsample: N=2, C=256, H=100, W=100, K=5, G=1, S=2.
// out[n,c,2h+a,2w+b] = sum_{dy,dx} mask[n,dy*5+dx,2h+a,2w+b] * feat[n,c,h+dy-2,w+dx-2]
//
// R1..R11 journal: anchor R8 = 38.1 us (LDS features, global masks).
// R11 showed compiler sinks batched loads (VGPR 32 -> ~2 loads in flight);
// occupancy 56% with dur unchanged -> bound by the per-thread chain of 50
// global mask loads (L2/L3 latency, no MLP). Conflicts ~1.9M across all
// layouts = benign 2-way b128 aliasing.
// R12: stage BOTH operands in LDS; compute loop has ZERO global loads.
//   Block = 8x8-px tile x 32 ch (4 waves; wave = 8 channels, lane = pixel).
//   - masks transposed at staging to [tap][px] f4 (m00,m01,m10,m11): 25.6KB,
//     shared by all 4 waves -> mask global traffic /4 vs R8; compute reads
//     1 f4/tap (lanes consecutive -> conflict-free).
//   - features channels-last [q][y][x] f4: 20KB, 2x b128/tap.
//   Per tap: 3 LDS reads + 16 v_pk_fma. Global loads only in 2 batched
//   staging bursts (~30/thread, independent -> MLP by construction).
//   45.6KB LDS -> 3 blocks/CU; stage/compute overlaps across blocks.

typedef float v2f __attribute__((ext_vector_type(2)));
typedef float v4f __attribute__((ext_vector_type(4)));

#define N_ 2
#define C_ 256
#define H_ 100
#define W_ 100
#define HW_ (H_ * W_)
#define OW_ (W_ * 2)
#define OH_ (H_ * 2)
#define OHW_ (HW_ * 4)
#define TS 8                        // pixels per tile side
#define HT 12                       // halo extent (TS+4)
#define NT 13                       // ceil(100/8)
#define FSTR 13                     // f4 stride of feature row
#define FQ (HT * FSTR)              // 156 f4 per quad plane
#define NCG 8                       // channel groups of 32

__global__ __launch_bounds__(256) void carafe_kernel(
    const float* __restrict__ feat,
    const float* __restrict__ mask,
    float* __restrict__ out) {

    __shared__ v4f lmq[25 * 64];        // masks: [tap][py*8+px] = 25,600 B
    __shared__ v4f lf4[8 * FQ];         // feats: [q][y][x], 19,968 B

    const int cg   = blockIdx.x;        // 0..7  (channels cg*32 .. cg*32+31)
    const int ti   = blockIdx.y;        // 0..168
    const int n    = blockIdx.z;
    const int tx = ti % NT, ty = ti / NT;
    const int x0 = tx * TS, y0 = ty * TS;
    const int t = threadIdx.x;

    // ---- stage masks, transposed to per-pixel quads ----
    {
        const float* mb = mask + n * (25 * OHW_);
#pragma unroll
        for (int r = 0; r < 7; ++r) {
            const int i = r * 256 + t;
            if (i < 25 * 64) {
                const int tap = i >> 6;
                const int pl  = i & 63;
                const int py = pl >> 3, px = pl & 7;
                const int oh = 2 * (y0 + py);
                const int ow = 2 * (x0 + px);
                v4f v = {0.f, 0.f, 0.f, 0.f};
                if ((oh < OH_) & (ow < OW_)) {
                    const float* p = mb + tap * OHW_ + oh * OW_ + ow;
                    const v2f r0 = *reinterpret_cast<const v2f*>(p);
                    const v2f r1 = *reinterpret_cast<const v2f*>(p + OW_);
                    v = (v4f){r0.x, r0.y, r1.x, r1.y};
                }
                lmq[i] = v;
            }
        }
    }
    // ---- stage features channels-last ----
    {
        const float* fb = feat + (n * C_ + cg * 32) * HW_;
#pragma unroll
        for (int r = 0; r < 5; ++r) {
            const int j = r * 256 + t;
            if (j < 8 * HT * HT) {
                const int q   = j / (HT * HT);
                const int rem = j % (HT * HT);
                const int y = rem / HT, x = rem % HT;
                const int yy = y0 - 2 + y;
                const int xx = x0 - 2 + x;
                v4f v = {0.f, 0.f, 0.f, 0.f};
                if (((unsigned)yy < (unsigned)H_) & ((unsigned)xx < (unsigned)W_)) {
                    const int o = (q * 4) * HW_ + yy * W_ + xx;
                    v.x = fb[o];
                    v.y = fb[o + HW_];
                    v.z = fb[o + 2 * HW_];
                    v.w = fb[o + 3 * HW_];
                }
                lf4[q * FSTR * HT + y * FSTR + x] = v;
            }
        }
    }
    __syncthreads();

    // ---- compute: wave = 8 channels, lane = pixel ----
    const int wv = t >> 6;              // 0..3
    const int lane = t & 63;
    const int py = lane >> 3, px = lane & 7;
    const int q0 = 2 * wv, q1 = 2 * wv + 1;

    v4f acc[8];                          // [c] = (o00, o01, o10, o11)
#pragma unroll
    for (int c = 0; c < 8; ++c) acc[c] = (v4f){0.f, 0.f, 0.f, 0.f};

#pragma unroll
    for (int dy = 0; dy < 5; ++dy) {
#pragma unroll
        for (int dx = 0; dx < 5; ++dx) {
            const int tap = dy * 5 + dx;
            const v4f mq = lmq[tap * 64 + lane];
            const v4f f0 = lf4[q0 * FQ + (py + dy) * FSTR + (px + dx)];  // c0..3
            const v4f f1 = lf4[q1 * FQ + (py + dy) * FSTR + (px + dx)];  // c4..7
#pragma unroll
            for (int k = 0; k < 4; ++k) {
                const v4f s0 = {f0[k], f0[k], f0[k], f0[k]};
                const v4f s1 = {f1[k], f1[k], f1[k], f1[k]};
                acc[k]     = __builtin_elementwise_fma(s0, mq, acc[k]);     // 2x v_pk_fma
                acc[4 + k] = __builtin_elementwise_fma(s1, mq, acc[4 + k]);
            }
        }
    }

    const int h = y0 + py, w = x0 + px;
    if ((h < H_) & (w < W_)) {
        float* ob = out + ((n * C_ + cg * 32 + wv * 8) * OHW_) + (2 * h) * OW_ + 2 * w;
#pragma unroll
        for (int c = 0; c < 8; ++c) {
            *reinterpret_cast<v2f*>(ob + c * OHW_)       = (v2f){acc[c].x, acc[c].y};
            *reinterpret_cast<v2f*>(ob + c * OHW_ + OW_) = (v2f){acc[c].z, acc[c].w};
        }
    }
}

extern "C" void kernel_launch(void* const* d_in, const int* in_sizes, int n_in,
                              void* d_out, int out_size, void* d_ws, size_t ws_size,
                              hipStream_t stream) {
    const float* feat = (const float*)d_in[0];
    const float* mask = (const float*)d_in[1];
    float* out = (float*)d_out;

    dim3 grid(NCG, NT * NT, N_);    // 8 x 169 x 2 = 2704 blocks
    carafe_kernel<<<grid, 256, 0, stream>>>(feat, mask, out);
}

// Round 13
// 37.088 us; speedup vs baseline: 1.4308x; 1.4308x over previous
//
#include <hip/hip_runtime.h>

// CARAFE naive upsample: N=2, C=256, H=100, W=100, K=5, G=1, S=2.
// out[n,c,2h+a,2w+b] = sum_{dy,dx} mask[n,dy*5+dx,2h+a,2w+b] * feat[n,c,h+dy-2,w+dx-2]
//
// Journal: R8 = 38.1 us ANCHOR (LDS features RSTR=29, global masks, 2560
// blocks). R11: occupancy 56% with dur unchanged -> occupancy not the lever;
// compiler re-sank batched loads (VGPR 32 -> ~2 mask loads in flight).
// R12: masks via LDS -> 53 us (LDS instr-count is a wall; masks stay global).
// R13: R8 + software-pipelined mask prefetch PINNED with sched_barrier(0).
//   dy-loop hand-unrolled to 5 stages, two static register sets (A/B).
//   Stage dy's 10 mask loads issue one stage early; sched_barrier(0) at
//   stage boundaries blocks the scheduler from sinking them. Steady-state
//   ~10-20 loads in flight/wave; waitcnt becomes counted vmcnt at use.

typedef float v2f __attribute__((ext_vector_type(2)));

#define N_ 2
#define C_ 256
#define H_ 100
#define W_ 100
#define CC 8
#define HW_ (H_ * W_)
#define OW_ (W_ * 2)
#define OHW_ (HW_ * 4)
#define NCHUNK (C_ / CC)          // 32
#define TW 25
#define TH 10
#define HX 29                     // halo cols (TW+4)
#define NROW 28                   // 14 halo rows x 2 channel-quads
#define RSTR 29                   // float4 row stride: >= HX and odd
#define TILES_X (W_ / TW)         // 4
#define TILES_Y (H_ / TH)         // 10
#define TILES (TILES_X * TILES_Y) // 40

__global__ __launch_bounds__(256) void carafe_kernel(
    const float* __restrict__ feat,
    const float* __restrict__ mask,
    float* __restrict__ out) {

    __shared__ float4 lds4[NROW * RSTR];   // 28*29*16 = 12,992 B

    const int cchunk = blockIdx.x;
    const int tile   = blockIdx.y;
    const int n      = blockIdx.z;
    const int tx = tile % TILES_X;
    const int ty = tile / TILES_X;
    const int x0 = tx * TW;
    const int y0 = ty * TH;
    const int t = threadIdx.x;
    const int lane = t & 31;
    const int g = t >> 5;

    // ---- stage features (identical to R8) ----
    {
        const float* fb = feat + (n * C_ + cchunk * CC) * HW_;
        const int xx = x0 - 2 + lane;
        const bool xok = (lane < HX) & ((unsigned)xx < (unsigned)W_);
#pragma unroll
        for (int r = 0; r < 4; ++r) {
            const int p = g * 4 + r;
            const int y = p >> 1;
            const int cq = p & 1;
            const int yy = y0 - 2 + y;
            float v0 = 0.f, v1 = 0.f, v2 = 0.f, v3 = 0.f;
            if (xok & ((unsigned)yy < (unsigned)H_) & (p < NROW)) {
                const int o = (cq * 4) * HW_ + yy * W_ + xx;
                v0 = fb[o];
                v1 = fb[o + HW_];
                v2 = fb[o + 2 * HW_];
                v3 = fb[o + 3 * HW_];
            }
            if ((p < NROW) & (lane < HX))
                lds4[p * RSTR + lane] = make_float4(v0, v1, v2, v3);
        }
    }
    __syncthreads();

    if (t >= TH * TW) return;              // 250 compute threads
    const int hl = t / TW;
    const int wl = t % TW;

    v2f a0[CC], a1[CC];
#pragma unroll
    for (int c = 0; c < CC; ++c) { a0[c] = (v2f){0.f, 0.f}; a1[c] = (v2f){0.f, 0.f}; }

    const int oh0 = 2 * (y0 + hl);
    const int ow0 = 2 * (x0 + wl);
    const float* mbase = mask + n * (25 * OHW_) + oh0 * OW_ + ow0;

    v2f m0A[5], m1A[5], m0B[5], m1B[5];

#define LOADM(MS0, MS1, dyv)                                                  \
    do {                                                                      \
        const float* mr_ = mbase + ((dyv) * 5) * OHW_;                        \
        _Pragma("unroll")                                                     \
        for (int dx = 0; dx < 5; ++dx) {                                      \
            MS0[dx] = *reinterpret_cast<const v2f*>(mr_ + dx * OHW_);         \
            MS1[dx] = *reinterpret_cast<const v2f*>(mr_ + dx * OHW_ + OW_);   \
        }                                                                     \
    } while (0)

#define STAGE(MS0, MS1, dyv)                                                  \
    do {                                                                      \
        const int ry_ = (hl + (dyv)) * 2;                                     \
        float4 lo_[5], hi_[5];                                                \
        _Pragma("unroll")                                                     \
        for (int dx = 0; dx < 5; ++dx) {                                      \
            lo_[dx] = lds4[ry_ * RSTR + wl + dx];                             \
            hi_[dx] = lds4[(ry_ + 1) * RSTR + wl + dx];                       \
        }                                                                     \
        _Pragma("unroll")                                                     \
        for (int dx = 0; dx < 5; ++dx) {                                      \
            const float f_[8] = {lo_[dx].x, lo_[dx].y, lo_[dx].z, lo_[dx].w,  \
                                 hi_[dx].x, hi_[dx].y, hi_[dx].z, hi_[dx].w}; \
            _Pragma("unroll")                                                 \
            for (int c = 0; c < CC; ++c) {                                    \
                const v2f fv_ = {f_[c], f_[c]};                               \
                a0[c] = __builtin_elementwise_fma(fv_, MS0[dx], a0[c]);       \
                a1[c] = __builtin_elementwise_fma(fv_, MS1[dx], a1[c]);       \
            }                                                                 \
        }                                                                     \
    } while (0)

    // ---- software pipeline: loads one stage ahead, pinned by sched_barrier ----
    LOADM(m0A, m1A, 0);
    LOADM(m0B, m1B, 1);
    __builtin_amdgcn_sched_barrier(0);
    STAGE(m0A, m1A, 0);
    LOADM(m0A, m1A, 2);
    __builtin_amdgcn_sched_barrier(0);
    STAGE(m0B, m1B, 1);
    LOADM(m0B, m1B, 3);
    __builtin_amdgcn_sched_barrier(0);
    STAGE(m0A, m1A, 2);
    LOADM(m0A, m1A, 4);
    __builtin_amdgcn_sched_barrier(0);
    STAGE(m0B, m1B, 3);
    __builtin_amdgcn_sched_barrier(0);
    STAGE(m0A, m1A, 4);

#undef LOADM
#undef STAGE

    float* ob = out + (n * C_ + cchunk * CC) * OHW_ + oh0 * OW_ + ow0;
#pragma unroll
    for (int c = 0; c < CC; ++c) {
        *reinterpret_cast<v2f*>(ob + c * OHW_) = a0[c];
        *reinterpret_cast<v2f*>(ob + c * OHW_ + OW_) = a1[c];
    }
}

extern "C" void kernel_launch(void* const* d_in, const int* in_sizes, int n_in,
                              void* d_out, int out_size, void* d_ws, size_t ws_size,
                              hipStream_t stream) {
    const float* feat = (const float*)d_in[0];
    const float* mask = (const float*)d_in[1];
    float* out = (float*)d_out;

    dim3 grid(NCHUNK, TILES, N_);   // 32 x 40 x 2 = 2560 blocks
    carafe_kernel<<<grid, 256, 0, stream>>>(feat, mask, out);
}